// Round 7
// baseline (349.935 us; speedup 1.0000x reference)
//
#include <hip/hip_runtime.h>
#include <math.h>

#define IN_DIM 128
#define HID 64
#define NEG_SLOPE 0.2f
#define CHUNK 4096
#define GCAP 6144

typedef __attribute__((ext_vector_type(8))) short bf16x8;
typedef __attribute__((ext_vector_type(4))) float f32x4;
typedef __attribute__((ext_vector_type(2))) float v2f;

__device__ __forceinline__ float wmax(float v){
  #pragma unroll
  for (int o = 32; o > 0; o >>= 1) v = fmaxf(v, __shfl_xor(v, o));
  return v;
}
__device__ __forceinline__ float wsum(float v){
  #pragma unroll
  for (int o = 32; o > 0; o >>= 1) v += __shfl_xor(v, o);
  return v;
}
__device__ __forceinline__ unsigned short f2bf(float f){
  union { float f; unsigned u; } v; v.f = f;
  unsigned r = v.u + 0x7fffu + ((v.u >> 16) & 1u);
  return (unsigned short)(r >> 16);
}
__device__ __forceinline__ float bl(unsigned u){
  union { unsigned u; float f; } v; v.u = u << 16; return v.f;
}
__device__ __forceinline__ float bh(unsigned u){
  union { unsigned u; float f; } v; v.u = u & 0xffff0000u; return v.f;
}
__device__ __forceinline__ v2f up2(unsigned u){
  v2f r; r[0] = bl(u); r[1] = bh(u); return r;
}

// non-temporal (no L2-allocate) access helpers for streaming operands
__device__ __forceinline__ unsigned nt_u32(const unsigned* p){
  return __builtin_nontemporal_load(p);
}
__device__ __forceinline__ float2 nt_f2(const float2* p){
  unsigned long long v = __builtin_nontemporal_load((const unsigned long long*)p);
  union { unsigned long long u; float2 f; } c; c.u = v; return c.f;
}
__device__ __forceinline__ float nt_f(const float* p){
  return __builtin_nontemporal_load(p);
}
__device__ __forceinline__ void nt_store_f2(float2 v, float2* p){
  union { unsigned long long u; float2 f; } c; c.f = v;
  __builtin_nontemporal_store(c.u, (unsigned long long*)p);
}
__device__ __forceinline__ void nt_store_f(float v, float* p){
  __builtin_nontemporal_store(v, p);
}
__device__ __forceinline__ void nt_store_f4(float a, float b, float c, float d, float* p){
  f32x4 v; v[0] = a; v[1] = b; v[2] = c; v[3] = d;
  __builtin_nontemporal_store(v, (f32x4*)p);
}

// race-safe in-place inclusive scan of sh[0..255], 256 threads
__device__ __forceinline__ void incl_scan256(int* sh, int tid){
  #pragma unroll
  for (int off = 1; off < 256; off <<= 1){
    int v = sh[tid];
    if (tid >= off) v += sh[tid - off];
    __syncthreads();
    sh[tid] = v;
    __syncthreads();
  }
}

// ---------- CSR build (sort-based) ----------

__global__ __launch_bounds__(256) void pack_hist(const int* __restrict__ ei, int E,
                                                 unsigned* __restrict__ packed,
                                                 int* __restrict__ binCnt){
  __shared__ int lh[256];
  int tid = threadIdx.x;
  lh[tid] = 0; __syncthreads();
  int base = blockIdx.x * CHUNK;
  #pragma unroll
  for (int j = 0; j < CHUNK / 256; j++){
    int e = base + j * 256 + tid;
    if (e < E){
      unsigned s = (unsigned)ei[e];
      unsigned d = (unsigned)ei[E + e];
      unsigned pk = (d << 16) | s;
      packed[e] = pk;
      atomicAdd(&lh[d >> 8], 1);
    }
  }
  __syncthreads();
  if (lh[tid] > 0) atomicAdd(&binCnt[tid], lh[tid]);
}

__global__ __launch_bounds__(256) void scan_bins(const int* __restrict__ binCnt,
                                                 int* __restrict__ binBase,
                                                 int* __restrict__ binCursor,
                                                 int* __restrict__ row_ptr,
                                                 int NG, int N, int E){
  __shared__ int sh[256];
  int tid = threadIdx.x;
  sh[tid] = (tid < NG) ? binCnt[tid] : 0;
  __syncthreads();
  incl_scan256(sh, tid);
  int excl = tid ? sh[tid - 1] : 0;
  if (tid < NG){ binBase[tid] = excl; binCursor[tid] = excl; }
  if (tid == 0) row_ptr[N] = E;
}

__global__ __launch_bounds__(256) void scatter_bins(const unsigned* __restrict__ packed, int E,
                                                    int* __restrict__ binCursor,
                                                    unsigned* __restrict__ binned){
  __shared__ int lh[256], lbase[256], gpos[256], lcur[256];
  __shared__ unsigned buf[CHUNK];
  int tid = threadIdx.x;
  lh[tid] = 0; __syncthreads();
  int base = blockIdx.x * CHUNK;
  int rem = E - base;
  unsigned v[CHUNK / 256];
  #pragma unroll
  for (int j = 0; j < CHUNK / 256; j++){
    int i = j * 256 + tid;
    if (i < rem){ v[j] = packed[base + i]; atomicAdd(&lh[v[j] >> 24], 1); }
  }
  __syncthreads();
  lbase[tid] = lh[tid]; __syncthreads();
  incl_scan256(lbase, tid);
  int myExcl = tid ? lbase[tid - 1] : 0;
  __syncthreads();
  lbase[tid] = myExcl;
  lcur[tid] = myExcl;
  if (lh[tid] > 0) gpos[tid] = atomicAdd(&binCursor[tid], lh[tid]);
  __syncthreads();
  #pragma unroll
  for (int j = 0; j < CHUNK / 256; j++){
    int i = j * 256 + tid;
    if (i < rem){
      int b = v[j] >> 24;
      int p = atomicAdd(&lcur[b], 1);
      buf[p] = v[j];
    }
  }
  __syncthreads();
  int cn = rem < CHUNK ? rem : CHUNK;
  for (int i = tid; i < cn; i += 256){
    unsigned u = buf[i];
    int b = u >> 24;
    binned[gpos[b] + (i - lbase[b])] = u;
  }
}

__global__ __launch_bounds__(256) void group_sort(const unsigned* __restrict__ binned,
                                                  const int* __restrict__ binBase,
                                                  const int* __restrict__ binCnt,
                                                  unsigned* __restrict__ sorted,
                                                  int* __restrict__ row_ptr, int N){
  __shared__ unsigned A[GCAP], B[GCAP];
  __shared__ int h2[256], rs[256], cur[256];
  int g = blockIdx.x, tid = threadIdx.x;
  int base = binBase[g];
  int cnt = binCnt[g]; if (cnt > GCAP) cnt = GCAP;
  h2[tid] = 0; __syncthreads();
  for (int i = tid; i < cnt; i += 256){
    unsigned u = binned[base + i];
    A[i] = u;
    atomicAdd(&h2[(u >> 16) & 255], 1);
  }
  __syncthreads();
  rs[tid] = h2[tid]; __syncthreads();
  incl_scan256(rs, tid);
  int excl = tid ? rs[tid - 1] : 0;
  __syncthreads();
  rs[tid] = excl; cur[tid] = excl;
  int d = g * 256 + tid;
  if (d < N) row_ptr[d] = base + excl;
  __syncthreads();
  for (int i = tid; i < cnt; i += 256){
    unsigned u = A[i];
    int p = atomicAdd(&cur[(u >> 16) & 255], 1);
    B[p] = u;
  }
  __syncthreads();
  for (int i = tid; i < cnt; i += 256)
    sorted[base + i] = B[i];
}

// ---------- dense compute ----------

__global__ void convert_w(const float* __restrict__ W1, const float* __restrict__ W2,
                          unsigned short* __restrict__ W1t, unsigned short* __restrict__ W2t){
  int tid = blockIdx.x * 256 + threadIdx.x;
  if (tid < 128 * 128){
    int n = tid >> 7, k = tid & 127;
    W1t[n * 128 + k] = f2bf(W1[k * 128 + n]);
  }
  int t2 = tid - 128 * 128;
  if (t2 >= 0 && t2 < 64 * 64){
    int n = t2 >> 6, k = t2 & 63;
    W2t[n * 64 + k] = f2bf(W2[k * 64 + n]);
  }
}

// MFMA bf16 GEMM, M-tile 128, 512 threads.
// Epilogue writes h in SLICE-MAJOR bf16 layout (64B rows) for the XCD-pinned gather:
//  HEADS==2: slice s in [0,4): dword (n, c) = pack(h0[s*16+c], h1[s*16+c]), c in [0,16)
//  HEADS==1: slice s in [0,2): dword (n, c) = pack(h[s*32+2c], h[s*32+2c+1]), c in [0,16)
// Plus fused attention coefficients from fp32 accumulators.
template<int K, int NC, int HEADS>
__global__ __launch_bounds__(512) void gemm_mfma(const float* __restrict__ X,
    const unsigned short* __restrict__ Wt, const float* __restrict__ asrc,
    const float* __restrict__ adst, unsigned* __restrict__ Hs,
    float* __restrict__ aa, int n_rows, int Nn)
{
  constexpr int MT = 128;
  constexpr int KP = K + 8;
  constexpr int CP = NC + 4;
  constexpr int MF = MT / 16;
  constexpr int NFt = NC / 16;
  constexpr int WPN = 8 / NFt;
  constexpr int MFW = MF / WPN;
  constexpr unsigned SM1 = (unsigned)(MT + NC) * KP * 2;
  constexpr unsigned SM2 = (unsigned)MT * CP * 4;
  __shared__ char smem[SM1 > SM2 ? SM1 : SM2];
  unsigned short* xa = (unsigned short*)smem;
  unsigned short* wl = xa + MT * KP;
  int tid = threadIdx.x;
  int n0 = blockIdx.x * MT;

  for (int idx = tid; idx < MT * (K / 4); idx += 512){
    int n = idx / (K / 4), k4 = idx % (K / 4);
    float4 v = make_float4(0.f, 0.f, 0.f, 0.f);
    if (n0 + n < n_rows) v = *(const float4*)&X[(size_t)(n0 + n) * K + k4 * 4];
    ushort4 pk; pk.x = f2bf(v.x); pk.y = f2bf(v.y); pk.z = f2bf(v.z); pk.w = f2bf(v.w);
    *(ushort4*)&xa[n * KP + k4 * 4] = pk;
  }
  for (int idx = tid; idx < NC * (K / 8); idx += 512){
    int n = idx / (K / 8), k8 = idx % (K / 8);
    uint4 v = *(const uint4*)&Wt[(size_t)n * K + k8 * 8];
    *(uint4*)&wl[n * KP + k8 * 8] = v;
  }
  __syncthreads();

  int lane = tid & 63, w = tid >> 6;
  int m = lane & 15, q = lane >> 4;
  int nf = w % NFt;
  int mseg = w / NFt;
  f32x4 acc[MFW];
  #pragma unroll
  for (int i = 0; i < MFW; i++)
    #pragma unroll
    for (int r = 0; r < 4; r++) acc[i][r] = 0.f;

  #pragma unroll
  for (int ks = 0; ks < K / 32; ks++){
    bf16x8 bg = *(const bf16x8*)&wl[(nf * 16 + m) * KP + ks * 32 + q * 8];
    #pragma unroll
    for (int i = 0; i < MFW; i++){
      bf16x8 af = *(const bf16x8*)&xa[((mseg * MFW + i) * 16 + m) * KP + ks * 32 + q * 8];
      acc[i] = __builtin_amdgcn_mfma_f32_16x16x32_bf16(af, bg, acc[i], 0, 0, 0);
    }
  }
  __syncthreads();
  float* C = (float*)smem;
  #pragma unroll
  for (int i = 0; i < MFW; i++)
    #pragma unroll
    for (int r = 0; r < 4; r++)
      C[((mseg * MFW + i) * 16 + q * 4 + r) * CP + nf * 16 + m] = acc[i][r];
  __syncthreads();

  int row = tid >> 2;
  int n = n0 + row;
  if (HEADS == 2){
    int sl = tid & 3;                 // slice 0..3, 16 channel-pairs
    float s0 = 0.f, s1 = 0.f, d0 = 0.f, d1 = 0.f;
    unsigned pk[16];
    #pragma unroll
    for (int c = 0; c < 16; c++){
      int ch = sl * 16 + c;
      float v0 = C[row * CP + ch];
      float v1 = C[row * CP + 64 + ch];
      s0 += v0 * asrc[ch];      d0 += v0 * adst[ch];
      s1 += v1 * asrc[64 + ch]; d1 += v1 * adst[64 + ch];
      pk[c] = (unsigned)f2bf(v0) | ((unsigned)f2bf(v1) << 16);
    }
    if (n < n_rows){
      uint4* dst = (uint4*)&Hs[((size_t)sl * Nn + n) * 16];
      #pragma unroll
      for (int q4 = 0; q4 < 4; q4++)
        dst[q4] = make_uint4(pk[q4*4], pk[q4*4+1], pk[q4*4+2], pk[q4*4+3]);
    }
    s0 += __shfl_xor(s0, 1); s1 += __shfl_xor(s1, 1);
    d0 += __shfl_xor(d0, 1); d1 += __shfl_xor(d1, 1);
    s0 += __shfl_xor(s0, 2); s1 += __shfl_xor(s1, 2);
    d0 += __shfl_xor(d0, 2); d1 += __shfl_xor(d1, 2);
    if (sl == 0 && n < n_rows)
      *(float4*)&aa[(size_t)n * 4] = make_float4(s0, s1, d0, d1);
  } else {
    int qt = tid & 3;                 // 16 channels each
    int sl = qt >> 1, half = qt & 1;
    float sp = 0.f, dp = 0.f;
    unsigned pk[8];
    #pragma unroll
    for (int c2 = 0; c2 < 8; c2++){
      int ch = qt * 16 + c2 * 2;
      float v0 = C[row * CP + ch];
      float v1 = C[row * CP + ch + 1];
      sp += v0 * asrc[ch] + v1 * asrc[ch + 1];
      dp += v0 * adst[ch] + v1 * adst[ch + 1];
      pk[c2] = (unsigned)f2bf(v0) | ((unsigned)f2bf(v1) << 16);
    }
    if (n < n_rows){
      uint4* dst = (uint4*)&Hs[((size_t)sl * Nn + n) * 16 + half * 8];
      dst[0] = make_uint4(pk[0], pk[1], pk[2], pk[3]);
      dst[1] = make_uint4(pk[4], pk[5], pk[6], pk[7]);
    }
    sp += __shfl_xor(sp, 1); dp += __shfl_xor(dp, 1);
    sp += __shfl_xor(sp, 2); dp += __shfl_xor(dp, 2);
    if (qt == 0 && n < n_rows){
      aa[(size_t)n * 2]     = sp;
      aa[(size_t)n * 2 + 1] = dp;
    }
  }
}

// ---------- per-edge softmax alphas (CSR order, coalesced, nt streams) ----------

__global__ void alpha1_k(const int* __restrict__ row_ptr, const unsigned* __restrict__ sorted,
                         const float* __restrict__ aa, float2* __restrict__ alpha,
                         float2* __restrict__ aself, int n_nodes){
  int d = (blockIdx.x * blockDim.x + threadIdx.x) >> 6;
  int lane = threadIdx.x & 63;
  if (d >= n_nodes) return;
  int rp0 = row_ptr[d];
  int deg = row_ptr[d + 1] - rp0;
  float2 adv = *(const float2*)&aa[d * 4 + 2];
  int s = -1;
  if (lane < deg) s = (int)(nt_u32(&sorted[rp0 + lane]) & 0xffffu);
  else if (lane == deg) s = d;
  float e0 = -INFINITY, e1 = -INFINITY;
  if (s >= 0){
    float2 asv = *(const float2*)&aa[s * 4];
    float t0 = asv.x + adv.x;
    float t1 = asv.y + adv.y;
    e0 = t0 >= 0.f ? t0 : NEG_SLOPE * t0;
    e1 = t1 >= 0.f ? t1 : NEG_SLOPE * t1;
  }
  float m0 = wmax(e0), m1 = wmax(e1);
  float p0 = (s >= 0) ? __expf(e0 - m0) : 0.f;
  float p1 = (s >= 0) ? __expf(e1 - m1) : 0.f;
  float al0 = p0 / (wsum(p0) + 1e-16f);
  float al1 = p1 / (wsum(p1) + 1e-16f);
  if (lane < deg)       nt_store_f2(make_float2(al0, al1), &alpha[rp0 + lane]);
  else if (lane == deg) aself[d] = make_float2(al0, al1);
}

__global__ void alpha2_k(const int* __restrict__ row_ptr, const unsigned* __restrict__ sorted,
                         const float* __restrict__ aa, float* __restrict__ alpha,
                         float* __restrict__ aself, int n_nodes){
  int d = (blockIdx.x * blockDim.x + threadIdx.x) >> 6;
  int lane = threadIdx.x & 63;
  if (d >= n_nodes) return;
  int rp0 = row_ptr[d];
  int deg = row_ptr[d + 1] - rp0;
  float ad = aa[d * 2 + 1];
  int s = -1;
  if (lane < deg) s = (int)(nt_u32(&sorted[rp0 + lane]) & 0xffffu);
  else if (lane == deg) s = d;
  float e = -INFINITY;
  if (s >= 0){
    float t = aa[s * 2 + 0] + ad;
    e = t >= 0.f ? t : NEG_SLOPE * t;
  }
  float m = wmax(e);
  float p = (s >= 0) ? __expf(e - m) : 0.f;
  float al = p / (wsum(p) + 1e-16f);
  if (lane < deg)       nt_store_f(al, &alpha[rp0 + lane]);
  else if (lane == deg) aself[d] = al;
}

// ---------- XCD-pinned sliced gather/aggregate, wide loads ----------
// 16 edge slots x 4 lanes x uint4(16B): per edge exactly one 64B line of the
// slice; per wave-instr 1KB moved (round-5 issue efficiency). Streams (sorted,
// alpha, x1) are non-temporal so only the 3.2MB h slice allocates in L2.
// L1: 4 slices x 64B; slice = (b&7)>>1 -> XCD pair per slice.
__global__ __launch_bounds__(256) void agg1s(const int* __restrict__ row_ptr,
    const unsigned* __restrict__ sorted, const float2* __restrict__ alpha,
    const float2* __restrict__ aself, const unsigned* __restrict__ h1s,
    const float* __restrict__ b1, float* __restrict__ x1, int Nn){
  int b = blockIdx.x;
  int slice = (b & 7) >> 1;
  int dg = ((b >> 3) << 1) + (b & 1);
  int d = dg * 4 + (threadIdx.x >> 6);
  if (d >= Nn) return;
  int lane = threadIdx.x & 63;
  int rp0 = row_ptr[d];
  int deg = row_ptr[d + 1] - rp0;
  int ne = deg + 1;
  int g2 = lane >> 2, c = lane & 3;
  const uint4* hbase = (const uint4*)(h1s + (size_t)slice * Nn * 16);
  v2f a0 = {0.f,0.f}, a1 = {0.f,0.f}, a2 = {0.f,0.f}, a3 = {0.f,0.f};
  #pragma unroll 2
  for (int j0 = 0; j0 < ne; j0 += 16){
    int j = j0 + g2;
    int eidx = rp0 + (j < deg ? j : 0);
    unsigned sv = nt_u32(&sorted[eidx]);
    float2 at = nt_f2(&alpha[eidx]);
    int sj; v2f av;
    if (j < deg){ sj = (int)(sv & 0xffffu); av[0] = at.x; av[1] = at.y; }
    else if (j == deg){ sj = d; float2 t = aself[d]; av[0] = t.x; av[1] = t.y; }
    else { sj = d; av[0] = 0.f; av[1] = 0.f; }
    uint4 hv = hbase[(size_t)sj * 4 + c];
    a0 = av * up2(hv.x) + a0;
    a1 = av * up2(hv.y) + a1;
    a2 = av * up2(hv.z) + a2;
    a3 = av * up2(hv.w) + a3;
  }
  float f[8] = {a0[0], a0[1], a1[0], a1[1], a2[0], a2[1], a3[0], a3[1]};
  #pragma unroll
  for (int i = 0; i < 8; i++){
    f[i] += __shfl_xor(f[i], 4);
    f[i] += __shfl_xor(f[i], 8);
    f[i] += __shfl_xor(f[i], 16);
    f[i] += __shfl_xor(f[i], 32);
  }
  if (lane < 4){
    int chb = slice * 16 + lane * 4;
    float r[4];
    #pragma unroll
    for (int i = 0; i < 4; i++){
      float v = 0.5f * (f[2*i] + f[2*i+1]) + b1[chb + i];   // head mean + bias
      r[i] = v > 0.f ? v : expm1f(v);                        // ELU
    }
    nt_store_f4(r[0], r[1], r[2], r[3], &x1[(size_t)d * 64 + chb]);
  }
}

// L2: 2 slices x 64B; slice = (b&7)>>2 -> 4 XCDs per slice.
__global__ __launch_bounds__(256) void agg2s(const int* __restrict__ row_ptr,
    const unsigned* __restrict__ sorted, const float* __restrict__ alpha,
    const float* __restrict__ aself, const unsigned* __restrict__ h2s,
    const float* __restrict__ b2, float* __restrict__ out, int Nn){
  int b = blockIdx.x;
  int slice = (b & 7) >> 2;
  int dg = ((b >> 3) << 2) + (b & 3);
  int d = dg * 4 + (threadIdx.x >> 6);
  if (d >= Nn) return;
  int lane = threadIdx.x & 63;
  int rp0 = row_ptr[d];
  int deg = row_ptr[d + 1] - rp0;
  int ne = deg + 1;
  int g2 = lane >> 2, c = lane & 3;
  const uint4* hbase = (const uint4*)(h2s + (size_t)slice * Nn * 16);
  v2f a0 = {0.f,0.f}, a1 = {0.f,0.f}, a2 = {0.f,0.f}, a3 = {0.f,0.f};
  #pragma unroll 2
  for (int j0 = 0; j0 < ne; j0 += 16){
    int j = j0 + g2;
    int eidx = rp0 + (j < deg ? j : 0);
    unsigned sv = nt_u32(&sorted[eidx]);
    float at = nt_f(&alpha[eidx]);
    int sj; float a;
    if (j < deg){ sj = (int)(sv & 0xffffu); a = at; }
    else if (j == deg){ sj = d; a = aself[d]; }
    else { sj = d; a = 0.f; }
    uint4 hv = hbase[(size_t)sj * 4 + c];
    v2f av = {a, a};
    a0 = av * up2(hv.x) + a0;
    a1 = av * up2(hv.y) + a1;
    a2 = av * up2(hv.z) + a2;
    a3 = av * up2(hv.w) + a3;
  }
  float f[8] = {a0[0], a0[1], a1[0], a1[1], a2[0], a2[1], a3[0], a3[1]};
  #pragma unroll
  for (int i = 0; i < 8; i++){
    f[i] += __shfl_xor(f[i], 4);
    f[i] += __shfl_xor(f[i], 8);
    f[i] += __shfl_xor(f[i], 16);
    f[i] += __shfl_xor(f[i], 32);
  }
  if (lane < 4){
    int chb = slice * 32 + lane * 8;   // 4 dwords -> 8 consecutive channels
    float r[8];
    #pragma unroll
    for (int i = 0; i < 8; i++) r[i] = f[i] + b2[chb + i];
    nt_store_f4(r[0], r[1], r[2], r[3], &out[(size_t)d * 64 + chb]);
    nt_store_f4(r[4], r[5], r[6], r[7], &out[(size_t)d * 64 + chb + 4]);
  }
}

extern "C" void kernel_launch(void* const* d_in, const int* in_sizes, int n_in,
                              void* d_out, int out_size, void* d_ws, size_t ws_size,
                              hipStream_t stream){
  const float* x     = (const float*)d_in[0];
  const int*   ei    = (const int*)d_in[1];
  const float* W1    = (const float*)d_in[2];
  const float* asrc1 = (const float*)d_in[3];
  const float* adst1 = (const float*)d_in[4];
  const float* b1    = (const float*)d_in[5];
  const float* W2    = (const float*)d_in[6];
  const float* asrc2 = (const float*)d_in[7];
  const float* adst2 = (const float*)d_in[8];
  const float* b2    = (const float*)d_in[9];
  float* out = (float*)d_out;
  int N = in_sizes[0] / IN_DIM;   // 50000 (< 65536 for 16-bit packing)
  int E = in_sizes[1] / 2;
  int NG = (N + 255) >> 8;
  int NBLK = (E + CHUNK - 1) / CHUNK;
  int ngrp = (N + 3) / 4;         // dst-groups of 4 waves

  char* p = (char*)d_ws;
  unsigned* h1s = (unsigned*)p;              p += (size_t)N * 64 * 4;   // 4 slices x [N][16] dwords
  unsigned* h2s = (unsigned*)p;              p += (size_t)N * 32 * 4;   // 2 slices x [N][16] dwords
  float* x1  = (float*)p;                    p += (size_t)N * 64 * 4;   // fp32 [N,64]
  float* aa1 = (float*)p;                    p += (size_t)N * 4 * 4;
  float* aa2 = (float*)p;                    p += (size_t)N * 2 * 4;
  unsigned* packed = (unsigned*)p;           p += (size_t)E * 4;
  unsigned* binned = (unsigned*)p;           p += (size_t)E * 4;
  unsigned* sorted = (unsigned*)p;           p += (size_t)E * 4;
  int* row_ptr   = (int*)p;                  p += (size_t)(N + 1) * 4;
  int* binCnt    = (int*)p;                  p += 256 * 4;
  int* binBase   = (int*)p;                  p += 256 * 4;
  int* binCursor = (int*)p;                  p += 256 * 4;
  float2* aself1 = (float2*)p;               p += (size_t)N * 8;
  float*  aself2 = (float*)p;                p += (size_t)N * 4;
  unsigned short* W1t = (unsigned short*)p;  p += 128 * 128 * 2;
  unsigned short* W2t = (unsigned short*)p;
  // aliases onto dead buffers:
  float2* alpha1 = (float2*)packed;   // E*8 B over packed+binned (dead after group_sort)
  float*  alpha2 = (float*)x1;        // E*4 B over x1 (dead after gemm2)

  hipMemsetAsync(binCnt, 0, 256 * sizeof(int), stream);
  convert_w<<<(128 * 128 + 64 * 64 + 255) / 256, 256, 0, stream>>>(W1, W2, W1t, W2t);
  pack_hist<<<NBLK, 256, 0, stream>>>(ei, E, packed, binCnt);
  scan_bins<<<1, 256, 0, stream>>>(binCnt, binBase, binCursor, row_ptr, NG, N, E);
  scatter_bins<<<NBLK, 256, 0, stream>>>(packed, E, binCursor, binned);
  group_sort<<<NG, 256, 0, stream>>>(binned, binBase, binCnt, sorted, row_ptr, N);
  gemm_mfma<128, 128, 2><<<(N + 127) / 128, 512, 0, stream>>>(
      x, W1t, asrc1, adst1, h1s, aa1, N, N);
  alpha1_k<<<ngrp, 256, 0, stream>>>(row_ptr, sorted, aa1, alpha1, aself1, N);
  agg1s<<<((ngrp + 1) / 2) * 8, 256, 0, stream>>>(
      row_ptr, sorted, alpha1, aself1, h1s, b1, x1, N);
  gemm_mfma<64, 64, 1><<<(N + 127) / 128, 512, 0, stream>>>(
      x1, W2t, asrc2, adst2, h2s, aa2, N, N);
  alpha2_k<<<ngrp, 256, 0, stream>>>(row_ptr, sorted, aa2, alpha2, aself2, N);
  agg2s<<<((ngrp + 3) / 4) * 8, 256, 0, stream>>>(
      row_ptr, sorted, alpha2, aself2, h2s, b2, out, N);
}

// Round 8
// 235.885 us; speedup vs baseline: 1.4835x; 1.4835x over previous
//
#include <hip/hip_runtime.h>
#include <math.h>

#define IN_DIM 128
#define HID 64
#define NEG_SLOPE 0.2f
#define CHUNK 4096
#define GCAP 6144

typedef __attribute__((ext_vector_type(8))) short bf16x8;
typedef __attribute__((ext_vector_type(4))) float f32x4;
typedef __attribute__((ext_vector_type(2))) float v2f;

__device__ __forceinline__ float wmax(float v){
  #pragma unroll
  for (int o = 32; o > 0; o >>= 1) v = fmaxf(v, __shfl_xor(v, o));
  return v;
}
__device__ __forceinline__ float wsum(float v){
  #pragma unroll
  for (int o = 32; o > 0; o >>= 1) v += __shfl_xor(v, o);
  return v;
}
__device__ __forceinline__ unsigned short f2bf(float f){
  union { float f; unsigned u; } v; v.f = f;
  unsigned r = v.u + 0x7fffu + ((v.u >> 16) & 1u);
  return (unsigned short)(r >> 16);
}
__device__ __forceinline__ float bl(unsigned u){
  union { unsigned u; float f; } v; v.u = u << 16; return v.f;
}
__device__ __forceinline__ float bh(unsigned u){
  union { unsigned u; float f; } v; v.u = u & 0xffff0000u; return v.f;
}
__device__ __forceinline__ v2f up2(unsigned u){
  v2f r; r[0] = bl(u); r[1] = bh(u); return r;
}

// race-safe in-place inclusive scan of sh[0..255], 256 threads
__device__ __forceinline__ void incl_scan256(int* sh, int tid){
  #pragma unroll
  for (int off = 1; off < 256; off <<= 1){
    int v = sh[tid];
    if (tid >= off) v += sh[tid - off];
    __syncthreads();
    sh[tid] = v;
    __syncthreads();
  }
}

// ---------- CSR build (sort-based) ----------

// Merged prep: blocks [0,NBLK) pack edges + coarse histogram;
// blocks [NBLK, NBLK+80) convert W1/W2 to bf16 transposed; seed row_ptr[N]=E.
__global__ __launch_bounds__(256) void prep(const int* __restrict__ ei, int E, int NBLK,
                                            unsigned* __restrict__ packed,
                                            int* __restrict__ binCnt,
                                            const float* __restrict__ W1,
                                            const float* __restrict__ W2,
                                            unsigned short* __restrict__ W1t,
                                            unsigned short* __restrict__ W2t,
                                            int* __restrict__ row_ptr, int N){
  int tid = threadIdx.x;
  if ((int)blockIdx.x < NBLK){
    __shared__ int lh[256];
    lh[tid] = 0; __syncthreads();
    int base = blockIdx.x * CHUNK;
    #pragma unroll
    for (int j = 0; j < CHUNK / 256; j++){
      int e = base + j * 256 + tid;
      if (e < E){
        unsigned s = (unsigned)ei[e];
        unsigned d = (unsigned)ei[E + e];
        packed[e] = (d << 16) | s;
        atomicAdd(&lh[d >> 8], 1);
      }
    }
    __syncthreads();
    if (lh[tid] > 0) atomicAdd(&binCnt[tid], lh[tid]);
  } else {
    int t = (blockIdx.x - NBLK) * 256 + tid;
    if (t < 128 * 128){
      int n = t >> 7, k = t & 127;
      W1t[n * 128 + k] = f2bf(W1[k * 128 + n]);
    }
    int t2 = t - 128 * 128;
    if (t2 >= 0 && t2 < 64 * 64){
      int n = t2 >> 6, k = t2 & 63;
      W2t[n * 64 + k] = f2bf(W2[k * 64 + n]);
    }
    if (t == 0) row_ptr[N] = E;
  }
}

// bin edges into coarse-bin-grouped array; bin bases computed by inline scan
__global__ __launch_bounds__(256) void scatter_bins(const unsigned* __restrict__ packed, int E,
                                                    const int* __restrict__ binCnt,
                                                    int* __restrict__ binOff,
                                                    unsigned* __restrict__ binned){
  __shared__ int bc[256], lh[256], lbase[256], gpos[256], lcur[256];
  __shared__ unsigned buf[CHUNK];
  int tid = threadIdx.x;
  int cg = binCnt[tid];
  bc[tid] = cg;
  lh[tid] = 0;
  __syncthreads();
  incl_scan256(bc, tid);
  int binBase_t = bc[tid] - cg;     // exclusive scan value for bin==tid
  int base = blockIdx.x * CHUNK;
  int rem = E - base;
  unsigned v[CHUNK / 256];
  #pragma unroll
  for (int j = 0; j < CHUNK / 256; j++){
    int i = j * 256 + tid;
    if (i < rem){ v[j] = packed[base + i]; atomicAdd(&lh[v[j] >> 24], 1); }
  }
  __syncthreads();
  lbase[tid] = lh[tid]; __syncthreads();
  incl_scan256(lbase, tid);
  int myExcl = tid ? lbase[tid - 1] : 0;
  __syncthreads();
  lbase[tid] = myExcl;
  lcur[tid] = myExcl;
  if (lh[tid] > 0) gpos[tid] = binBase_t + atomicAdd(&binOff[tid], lh[tid]);
  __syncthreads();
  #pragma unroll
  for (int j = 0; j < CHUNK / 256; j++){
    int i = j * 256 + tid;
    if (i < rem){
      int b = v[j] >> 24;
      int p = atomicAdd(&lcur[b], 1);
      buf[p] = v[j];
    }
  }
  __syncthreads();
  int cn = rem < CHUNK ? rem : CHUNK;
  for (int i = tid; i < cn; i += 256){
    unsigned u = buf[i];
    int b = u >> 24;
    binned[gpos[b] + (i - lbase[b])] = u;
  }
}

// per coarse bin: LDS counting sort by dst&255 -> sorted edges + CSR row_ptr
__global__ __launch_bounds__(256) void group_sort(const unsigned* __restrict__ binned,
                                                  const int* __restrict__ binCnt,
                                                  unsigned* __restrict__ sorted,
                                                  int* __restrict__ row_ptr, int N){
  __shared__ unsigned A[GCAP], B[GCAP];
  __shared__ int sc[256], h2[256], rs[256], cur[256];
  int g = blockIdx.x, tid = threadIdx.x;
  int cg = binCnt[tid];
  sc[tid] = cg;
  h2[tid] = 0;
  __syncthreads();
  incl_scan256(sc, tid);
  int base = sc[g] - binCnt[g];     // broadcast read: exclusive base of bin g
  int cnt = binCnt[g]; if (cnt > GCAP) cnt = GCAP;
  __syncthreads();
  for (int i = tid; i < cnt; i += 256){
    unsigned u = binned[base + i];
    A[i] = u;
    atomicAdd(&h2[(u >> 16) & 255], 1);
  }
  __syncthreads();
  rs[tid] = h2[tid]; __syncthreads();
  incl_scan256(rs, tid);
  int excl = tid ? rs[tid - 1] : 0;
  __syncthreads();
  rs[tid] = excl; cur[tid] = excl;
  int d = g * 256 + tid;
  if (d < N) row_ptr[d] = base + excl;
  __syncthreads();
  for (int i = tid; i < cnt; i += 256){
    unsigned u = A[i];
    int p = atomicAdd(&cur[(u >> 16) & 255], 1);
    B[p] = u;
  }
  __syncthreads();
  for (int i = tid; i < cnt; i += 256)
    sorted[base + i] = B[i];
}

// ---------- dense compute ----------

// MFMA bf16 GEMM, M-tile 128, 512 threads; fused bf16 H store + attention coefs.
template<int K, int NC, int HEADS>
__global__ __launch_bounds__(512) void gemm_mfma(const float* __restrict__ X,
    const unsigned short* __restrict__ Wt, const float* __restrict__ asrc,
    const float* __restrict__ adst, unsigned short* __restrict__ Hb,
    float* __restrict__ aa, int n_rows)
{
  constexpr int MT = 128;
  constexpr int KP = K + 8;
  constexpr int CP = NC + 4;
  constexpr int MF = MT / 16;
  constexpr int NFt = NC / 16;
  constexpr int WPN = 8 / NFt;
  constexpr int MFW = MF / WPN;
  constexpr unsigned SM1 = (unsigned)(MT + NC) * KP * 2;
  constexpr unsigned SM2 = (unsigned)MT * CP * 4;
  __shared__ char smem[SM1 > SM2 ? SM1 : SM2];
  unsigned short* xa = (unsigned short*)smem;
  unsigned short* wl = xa + MT * KP;
  int tid = threadIdx.x;
  int n0 = blockIdx.x * MT;

  for (int idx = tid; idx < MT * (K / 4); idx += 512){
    int n = idx / (K / 4), k4 = idx % (K / 4);
    float4 v = make_float4(0.f, 0.f, 0.f, 0.f);
    if (n0 + n < n_rows) v = *(const float4*)&X[(size_t)(n0 + n) * K + k4 * 4];
    ushort4 pk; pk.x = f2bf(v.x); pk.y = f2bf(v.y); pk.z = f2bf(v.z); pk.w = f2bf(v.w);
    *(ushort4*)&xa[n * KP + k4 * 4] = pk;
  }
  for (int idx = tid; idx < NC * (K / 8); idx += 512){
    int n = idx / (K / 8), k8 = idx % (K / 8);
    uint4 v = *(const uint4*)&Wt[(size_t)n * K + k8 * 8];
    *(uint4*)&wl[n * KP + k8 * 8] = v;
  }
  __syncthreads();

  int lane = tid & 63, w = tid >> 6;
  int m = lane & 15, q = lane >> 4;
  int nf = w % NFt;
  int mseg = w / NFt;
  f32x4 acc[MFW];
  #pragma unroll
  for (int i = 0; i < MFW; i++)
    #pragma unroll
    for (int r = 0; r < 4; r++) acc[i][r] = 0.f;

  #pragma unroll
  for (int ks = 0; ks < K / 32; ks++){
    bf16x8 bg = *(const bf16x8*)&wl[(nf * 16 + m) * KP + ks * 32 + q * 8];
    #pragma unroll
    for (int i = 0; i < MFW; i++){
      bf16x8 af = *(const bf16x8*)&xa[((mseg * MFW + i) * 16 + m) * KP + ks * 32 + q * 8];
      acc[i] = __builtin_amdgcn_mfma_f32_16x16x32_bf16(af, bg, acc[i], 0, 0, 0);
    }
  }
  __syncthreads();
  float* C = (float*)smem;
  #pragma unroll
  for (int i = 0; i < MFW; i++)
    #pragma unroll
    for (int r = 0; r < 4; r++)
      C[((mseg * MFW + i) * 16 + q * 4 + r) * CP + nf * 16 + m] = acc[i][r];
  __syncthreads();

  constexpr int CH = NC / 4;
  int row = tid >> 2;
  int c0 = (tid & 3) * CH;
  int n = n0 + row;
  int head = (HEADS == 2) ? (c0 >> 6) : 0;
  float s_p = 0.f, d_p = 0.f;
  unsigned short hb[CH];
  #pragma unroll
  for (int c = 0; c < CH; c += 4){
    f32x4 v = *(const f32x4*)&C[row * CP + c0 + c];
    #pragma unroll
    for (int u = 0; u < 4; u++){
      int ch = (c0 + c + u) & 63;
      s_p += v[u] * asrc[head * 64 + ch];
      d_p += v[u] * adst[head * 64 + ch];
      hb[c + u] = f2bf(v[u]);
    }
  }
  if (n < n_rows){
    #pragma unroll
    for (int c = 0; c < CH; c += 8){
      uint4 pk;
      pk.x = (unsigned)hb[c]     | ((unsigned)hb[c + 1] << 16);
      pk.y = (unsigned)hb[c + 2] | ((unsigned)hb[c + 3] << 16);
      pk.z = (unsigned)hb[c + 4] | ((unsigned)hb[c + 5] << 16);
      pk.w = (unsigned)hb[c + 6] | ((unsigned)hb[c + 7] << 16);
      *(uint4*)&Hb[(size_t)n * NC + c0 + c] = pk;
    }
  }
  s_p += __shfl_xor(s_p, 1);
  d_p += __shfl_xor(d_p, 1);
  if (HEADS == 2){
    if ((tid & 1) == 0 && n < n_rows){
      aa[(size_t)n * 4 + head]     = s_p;
      aa[(size_t)n * 4 + 2 + head] = d_p;
    }
  } else {
    s_p += __shfl_xor(s_p, 2);
    d_p += __shfl_xor(d_p, 2);
    if ((tid & 3) == 0 && n < n_rows){
      aa[(size_t)n * 2]     = s_p;
      aa[(size_t)n * 2 + 1] = d_p;
    }
  }
}

// ---------- softmax + aggregation (CSR, fused — round-5 form) ----------

__global__ void agg_layer1(const int* __restrict__ row_ptr, const unsigned* __restrict__ sorted,
                           const float* __restrict__ aa, const unsigned short* __restrict__ h1b,
                           const float* __restrict__ b1, float* __restrict__ x1, int n_nodes){
  int d = (blockIdx.x * blockDim.x + threadIdx.x) >> 6;
  int lane = threadIdx.x & 63;
  if (d >= n_nodes) return;
  int rp0 = row_ptr[d];
  int deg = row_ptr[d + 1] - rp0;
  float2 adv = *(const float2*)&aa[d * 4 + 2];
  int s = -1;
  if (lane < deg) s = (int)(sorted[rp0 + lane] & 0xffffu);
  else if (lane == deg) s = d;
  float e0 = -INFINITY, e1 = -INFINITY;
  if (s >= 0){
    float2 asv = *(const float2*)&aa[s * 4];
    float t0 = asv.x + adv.x;
    float t1 = asv.y + adv.y;
    e0 = t0 >= 0.f ? t0 : NEG_SLOPE * t0;
    e1 = t1 >= 0.f ? t1 : NEG_SLOPE * t1;
  }
  float m0 = wmax(e0), m1 = wmax(e1);
  float p0 = (s >= 0) ? __expf(e0 - m0) : 0.f;
  float p1 = (s >= 0) ? __expf(e1 - m1) : 0.f;
  float al0 = p0 / (wsum(p0) + 1e-16f);
  float al1 = p1 / (wsum(p1) + 1e-16f);
  int ne = deg + 1;
  int g = lane >> 4, c = lane & 15;
  v2f acc[4] = {{0.f,0.f},{0.f,0.f},{0.f,0.f},{0.f,0.f}};
  #pragma unroll 2
  for (int j0 = 0; j0 < ne; j0 += 4){
    int j = j0 + g;
    int sj = __shfl(s, j);
    float a0 = __shfl(al0, j);
    float a1 = __shfl(al1, j);
    if (j < ne){
      uint4 v = ((const uint4*)(h1b + (size_t)sj * 128))[c];
      float a = (c < 8) ? a0 : a1;
      v2f av = {a, a};
      acc[0] = av * up2(v.x) + acc[0];
      acc[1] = av * up2(v.y) + acc[1];
      acc[2] = av * up2(v.z) + acc[2];
      acc[3] = av * up2(v.w) + acc[3];
    }
  }
  float accf[8] = {acc[0][0], acc[0][1], acc[1][0], acc[1][1],
                   acc[2][0], acc[2][1], acc[3][0], acc[3][1]};
  #pragma unroll
  for (int i = 0; i < 8; i++){
    accf[i] += __shfl_xor(accf[i], 16);
    accf[i] += __shfl_xor(accf[i], 32);
  }
  float outv[8];
  #pragma unroll
  for (int i = 0; i < 8; i++){
    float o = __shfl_xor(accf[i], 8);
    outv[i] = 0.5f * (accf[i] + o);
  }
  if (g == 0 && c < 8){
    float r[8];
    #pragma unroll
    for (int i = 0; i < 8; i++){
      float v = outv[i] + b1[c * 8 + i];
      r[i] = v > 0.f ? v : expm1f(v);
    }
    float* p = &x1[(size_t)d * 64 + c * 8];
    *(float4*)p       = make_float4(r[0], r[1], r[2], r[3]);
    *(float4*)(p + 4) = make_float4(r[4], r[5], r[6], r[7]);
  }
}

__global__ void agg_layer2(const int* __restrict__ row_ptr, const unsigned* __restrict__ sorted,
                           const float* __restrict__ aa, const unsigned short* __restrict__ h2b,
                           const float* __restrict__ b2, float* __restrict__ out, int n_nodes){
  int d = (blockIdx.x * blockDim.x + threadIdx.x) >> 6;
  int lane = threadIdx.x & 63;
  if (d >= n_nodes) return;
  int rp0 = row_ptr[d];
  int deg = row_ptr[d + 1] - rp0;
  float ad = aa[d * 2 + 1];
  int s = -1;
  if (lane < deg) s = (int)(sorted[rp0 + lane] & 0xffffu);
  else if (lane == deg) s = d;
  float e = -INFINITY;
  if (s >= 0){
    float t = aa[s * 2 + 0] + ad;
    e = t >= 0.f ? t : NEG_SLOPE * t;
  }
  float m = wmax(e);
  float p = (s >= 0) ? __expf(e - m) : 0.f;
  float al = p / (wsum(p) + 1e-16f);
  int ne = deg + 1;
  int g = lane >> 3, c = lane & 7;
  v2f acc[4] = {{0.f,0.f},{0.f,0.f},{0.f,0.f},{0.f,0.f}};
  #pragma unroll 2
  for (int j0 = 0; j0 < ne; j0 += 8){
    int j = j0 + g;
    int sj = __shfl(s, j);
    float a = __shfl(al, j);
    if (j < ne){
      uint4 v = ((const uint4*)(h2b + (size_t)sj * 64))[c];
      v2f av = {a, a};
      acc[0] = av * up2(v.x) + acc[0];
      acc[1] = av * up2(v.y) + acc[1];
      acc[2] = av * up2(v.z) + acc[2];
      acc[3] = av * up2(v.w) + acc[3];
    }
  }
  float accf[8] = {acc[0][0], acc[0][1], acc[1][0], acc[1][1],
                   acc[2][0], acc[2][1], acc[3][0], acc[3][1]};
  #pragma unroll
  for (int i = 0; i < 8; i++){
    accf[i] += __shfl_xor(accf[i], 8);
    accf[i] += __shfl_xor(accf[i], 16);
    accf[i] += __shfl_xor(accf[i], 32);
  }
  if (lane < 8){
    float r[8];
    #pragma unroll
    for (int i = 0; i < 8; i++) r[i] = accf[i] + b2[lane * 8 + i];
    float* q = &out[(size_t)d * 64 + lane * 8];
    *(float4*)q       = make_float4(r[0], r[1], r[2], r[3]);
    *(float4*)(q + 4) = make_float4(r[4], r[5], r[6], r[7]);
  }
}

extern "C" void kernel_launch(void* const* d_in, const int* in_sizes, int n_in,
                              void* d_out, int out_size, void* d_ws, size_t ws_size,
                              hipStream_t stream){
  const float* x     = (const float*)d_in[0];
  const int*   ei    = (const int*)d_in[1];
  const float* W1    = (const float*)d_in[2];
  const float* asrc1 = (const float*)d_in[3];
  const float* adst1 = (const float*)d_in[4];
  const float* b1    = (const float*)d_in[5];
  const float* W2    = (const float*)d_in[6];
  const float* asrc2 = (const float*)d_in[7];
  const float* adst2 = (const float*)d_in[8];
  const float* b2    = (const float*)d_in[9];
  float* out = (float*)d_out;
  int N = in_sizes[0] / IN_DIM;   // 50000 (< 65536 for 16-bit packing)
  int E = in_sizes[1] / 2;
  int NG = (N + 255) >> 8;
  int NBLK = (E + CHUNK - 1) / CHUNK;
  int ngrp = (N + 3) / 4;

  char* p = (char*)d_ws;
  unsigned short* h1b = (unsigned short*)p;  p += (size_t)N * 128 * 2;
  unsigned short* h2b = (unsigned short*)p;  p += (size_t)N * 64 * 2;
  float* x1  = (float*)p;                    p += (size_t)N * 64 * 4;
  float* aa1 = (float*)p;                    p += (size_t)N * 4 * 4;
  float* aa2 = (float*)p;                    p += (size_t)N * 2 * 4;
  unsigned* packed = (unsigned*)p;           p += (size_t)E * 4;
  unsigned* binned = (unsigned*)p;           p += (size_t)E * 4;
  unsigned* sorted = (unsigned*)p;           p += (size_t)E * 4;
  int* row_ptr   = (int*)p;                  p += (size_t)(N + 1) * 4;
  int* binCnt    = (int*)p;                  p += 256 * 4;
  int* binOff    = (int*)p;                  p += 256 * 4;
  unsigned short* W1t = (unsigned short*)p;  p += 128 * 128 * 2;
  unsigned short* W2t = (unsigned short*)p;

  hipMemsetAsync(binCnt, 0, 512 * sizeof(int), stream);   // binCnt + binOff
  prep<<<NBLK + 80, 256, 0, stream>>>(ei, E, NBLK, packed, binCnt,
                                      W1, W2, W1t, W2t, row_ptr, N);
  scatter_bins<<<NBLK, 256, 0, stream>>>(packed, E, binCnt, binOff, binned);
  group_sort<<<NG, 256, 0, stream>>>(binned, binCnt, sorted, row_ptr, N);
  gemm_mfma<128, 128, 2><<<(N + 127) / 128, 512, 0, stream>>>(
      x, W1t, asrc1, adst1, h1b, aa1, N);
  agg_layer1<<<ngrp, 256, 0, stream>>>(row_ptr, sorted, aa1, h1b, b1, x1, N);
  gemm_mfma<64, 64, 1><<<(N + 127) / 128, 512, 0, stream>>>(
      x1, W2t, asrc2, adst2, h2b, aa2, N);
  agg_layer2<<<ngrp, 256, 0, stream>>>(row_ptr, sorted, aa2, h2b, b2, out, N);
}